// Round 5
// baseline (543.680 us; speedup 1.0000x reference)
//
#include <hip/hip_runtime.h>

// Problem constants
#define S_DIM 8192
#define K_DIM 1024
#define RO_DIM 4096
#define O_DIM 64
#define SO (S_DIM * O_DIM)
#define NSLICE 16  // N/256 partial slices

typedef __attribute__((ext_vector_type(8))) __bf16 bf16x8;
typedef __attribute__((ext_vector_type(4))) float floatx4;
typedef __attribute__((ext_vector_type(4))) unsigned short ushx4;
typedef __attribute__((ext_vector_type(8))) unsigned short ushx8;

__device__ inline unsigned short f2bf(float f) {
  unsigned u = __builtin_bit_cast(unsigned, f);
  u += 0x7fff + ((u >> 16) & 1);  // round-to-nearest-even
  return (unsigned short)(u >> 16);
}
__device__ inline float bf2f(unsigned short h) {
  unsigned u = ((unsigned)h) << 16;
  return __builtin_bit_cast(float, u);
}

template <int MB, int NB>
__device__ __forceinline__ void mfmaq(floatx4 (&acc)[8][4], const bf16x8 (&afr)[4][2],
                                      const bf16x8 (&bfr)[4][2]) {
  __builtin_amdgcn_s_setprio(1);
#pragma unroll
  for (int m = 0; m < 4; ++m)
#pragma unroll
    for (int n = 0; n < 2; ++n) {
      acc[MB + m][NB + n] = __builtin_amdgcn_mfma_f32_16x16x32_bf16(
          afr[m][0], bfr[NB + n][0], acc[MB + m][NB + n], 0, 0, 0);
      acc[MB + m][NB + n] = __builtin_amdgcn_mfma_f32_16x16x32_bf16(
          afr[m][1], bfr[NB + n][1], acc[MB + m][NB + n], 0, 0, 0);
    }
  __builtin_amdgcn_s_setprio(0);
}

#define BAR() __builtin_amdgcn_s_barrier()
#define LGKM0() asm volatile("s_waitcnt lgkmcnt(0)" ::: "memory")
#define SB0() __builtin_amdgcn_sched_barrier(0)

// ---------------------------------------------------------------- fused single-dispatch kernel
// R5: regular (non-cooperative) launch, 256 blocks x 512 threads = 1 block/CU.
// R4 post-mortem: dispatch-overhead model is ~11us for 1 dispatch, +~30us per
// extra dispatch (R0/R2/R3/R4 linear fit) -> single dispatch saves ~60us vs R3.
// Cooperative machinery was the R4 disaster (424us kernel, 0.9% occupancy);
// here the grid sync is a hand-rolled inline spin (threadfence + agent-scope
// atomic + s_sleep), and the final reduce needs NO second sync: the 16th block
// to finish a 256-row stripe (atomicAdd on done[by]) reduces that stripe.
// R4 passed => 256x512 @132KB LDS co-residency is proven; regular dispatch
// fills all 256 CUs breadth-first.
// GEMM section byte-identical to R3's verified 85us pipeline (quadrant phases,
// stages q0->A(kt+1)h1, q2->B(kt+2)h0, q3->B(kt+2)h1+A(kt+2)h0, vmcnt(6) after
// q3's MFMA, XOR k-chunk swizzle, XCD remap: XCD x owns bx in {2x,2x+1}).
__global__ __launch_bounds__(512, 2) void fused_kernel(const float* __restrict__ X,
                                                       const float* __restrict__ W,
                                                       const float* __restrict__ bias,
                                                       const float* __restrict__ lam,
                                                       unsigned short* __restrict__ Xb,
                                                       unsigned short* __restrict__ Wb,
                                                       unsigned short* __restrict__ partial,
                                                       int* __restrict__ ctr,  // [0]=bar, [1+by]=done
                                                       float* __restrict__ Y) {
  __shared__ __align__(16) unsigned char smem[135168];  // 128KB buffers + 4KB lamsh
  __shared__ int lastFlag;
  unsigned short* sm = (unsigned short*)smem;
  float* lamsh = (float*)(smem + 131072);  // [256][4]

  const int t = threadIdx.x;

  // ================= stage 1: cast (branch-free: X boundary = iteration boundary) =================
  {
    const int base = blockIdx.x * 512 + t;  // 0..131071
    const float4* X4 = (const float4*)X;
#pragma unroll 2
    for (int it = 0; it < 16; ++it) {       // 16*131072 = |X|/4
      int g = it * 131072 + base;
      float4 v = X4[g];
      ushx4 o;
      o.x = f2bf(v.x); o.y = f2bf(v.y); o.z = f2bf(v.z); o.w = f2bf(v.w);
      *(ushx4*)(Xb + (size_t)g * 4) = o;
    }
    const float4* W4 = (const float4*)W;
#pragma unroll 2
    for (int it = 0; it < 8; ++it) {        // 8*131072 = |W|/4
      int g = it * 131072 + base;
      float4 v = W4[g];
      ushx4 o;
      o.x = f2bf(v.x); o.y = f2bf(v.y); o.z = f2bf(v.z); o.w = f2bf(v.w);
      *(ushx4*)(Wb + (size_t)g * 4) = o;
    }
  }
  // ---- manual device barrier (release: all casts visible; acquire on exit) ----
  __threadfence();
  __syncthreads();
  if (t == 0) {
    __hip_atomic_fetch_add(&ctr[0], 1, __ATOMIC_ACQ_REL, __HIP_MEMORY_SCOPE_AGENT);
    while (__hip_atomic_load(&ctr[0], __ATOMIC_ACQUIRE, __HIP_MEMORY_SCOPE_AGENT) < 256)
      __builtin_amdgcn_s_sleep(32);
  }
  __syncthreads();
  __threadfence();

  // ================= stage 2: persistent GEMM (R3 pipeline, 2 reps) =================
  const int lane = t & 63;
  const int w = t >> 6;
  const int wm = w >> 2;   // M half: rows wm*128..+127
  const int wn = w & 3;    // N quarter = rule index within block
  const int quad = lane >> 4;
  const int l16 = lane & 15;

  // XCD-locality remap on 256 blocks: hw XCD = id%8; XCD x owns bx in {2x,2x+1}.
  const int id = blockIdx.x;
  const int x = id & 7;
  const int j = id >> 3;                 // 0..31
  const int bx = 2 * x + (j & 1);
  const int by0 = j >> 1;                // 0..15; rep adds +16
  const int gn0 = bx * 256;

  const int rowt = t >> 3;               // 0..63
  const int gcc = (t & 7) ^ (rowt & 7);
  const size_t goff = (size_t)rowt * K_DIM + (size_t)gcc * 8;
  const unsigned short* Bbase = Wb + (size_t)gn0 * K_DIM;

  const int cA0 = ((quad) ^ (l16 & 7)) * 8;      // k-chunk ks=0, swizzled
  const int cA1 = ((4 + quad) ^ (l16 & 7)) * 8;  // k-chunk ks=1, swizzled

  for (int rep = 0; rep < 2; ++rep) {
    const int by = by0 + rep * 16;
    const int gm0 = by * 256;
    const unsigned short* Abase = Xb + (size_t)gm0 * K_DIM;

    auto STAGE = [&](const unsigned short* gbase, int half, int ktile, int slotOff) {
#pragma unroll
      for (int jj = 0; jj < 2; ++jj) {
        const unsigned short* src =
            gbase + (size_t)(half * 128 + jj * 64) * K_DIM + ktile * 64 + goff;
        __builtin_amdgcn_global_load_lds(
            (const __attribute__((address_space(1))) void*)src,
            (__attribute__((address_space(3))) void*)(sm + slotOff + jj * 4096 + t * 8),
            16, 0, 0);
      }
    };

    // protect LDS from previous rep's epilogue readers (and cast stage)
    __syncthreads();

    // prologue: tile0 full (buf0), tile1 B halves + A h0 (buf1): 14 loads.
    STAGE(Abase, 0, 0, 0);
    STAGE(Abase, 1, 0, 8192);
    STAGE(Bbase, 0, 0, 16384);
    STAGE(Bbase, 1, 0, 24576);
    STAGE(Bbase, 0, 1, 32768 + 16384);
    STAGE(Bbase, 1, 1, 32768 + 24576);
    STAGE(Abase, 0, 1, 32768 + 0);

    {
      int i = t;
      lamsh[i] = lam[(size_t)(gm0 + (i >> 2)) * 64 + bx * 4 + (i & 3)];
      i = t + 512;
      lamsh[i] = lam[(size_t)(gm0 + (i >> 2)) * 64 + bx * 4 + (i & 3)];
    }
    asm volatile("s_waitcnt vmcnt(6)" ::: "memory");
    BAR();

    // acc init = bias (exact fold); bias loads are older than all loop stages.
    floatx4 acc[8][4];
#pragma unroll
    for (int ni = 0; ni < 4; ++ni) {
      float bv = bias[gn0 + wn * 64 + ni * 16 + l16];
#pragma unroll
      for (int mi = 0; mi < 8; ++mi) acc[mi][ni] = (floatx4){bv, bv, bv, bv};
    }

    for (int kt = 0; kt < 16; ++kt) {
      const int b = kt & 1;
      const unsigned short* As = sm + b * 32768 + wm * 8192 + l16 * 64;
      const unsigned short* Bs = sm + b * 32768 + 16384 + wn * 4096 + l16 * 64;
      const int bufN = (b ^ 1) * 32768;  // tile kt+1's buffer
      const int bufC = b * 32768;        // tile kt+2's buffer (== current)

      bf16x8 afr[4][2], bfr[4][2];

      // ---- q0: read A mi0-3 + B ni0-1; stage A(kt+1) h1
#pragma unroll
      for (int m = 0; m < 4; ++m) {
        afr[m][0] = *(const bf16x8*)(As + m * 1024 + cA0);
        afr[m][1] = *(const bf16x8*)(As + m * 1024 + cA1);
      }
#pragma unroll
      for (int n = 0; n < 2; ++n) {
        bfr[n][0] = *(const bf16x8*)(Bs + n * 1024 + cA0);
        bfr[n][1] = *(const bf16x8*)(Bs + n * 1024 + cA1);
      }
      if (kt < 15) STAGE(Abase, 1, kt + 1, bufN + 8192);
      BAR();
      LGKM0();
      SB0();
      mfmaq<0, 0>(acc, afr, bfr);
      BAR();

      // ---- q1: read B ni2-3
#pragma unroll
      for (int n = 2; n < 4; ++n) {
        bfr[n][0] = *(const bf16x8*)(Bs + n * 1024 + cA0);
        bfr[n][1] = *(const bf16x8*)(Bs + n * 1024 + cA1);
      }
      BAR();
      LGKM0();
      SB0();
      mfmaq<0, 2>(acc, afr, bfr);
      BAR();

      // ---- q2: read A mi4-7; stage B(kt+2) h0
#pragma unroll
      for (int m = 0; m < 4; ++m) {
        afr[m][0] = *(const bf16x8*)(As + (4 + m) * 1024 + cA0);
        afr[m][1] = *(const bf16x8*)(As + (4 + m) * 1024 + cA1);
      }
      if (kt < 14) STAGE(Bbase, 0, kt + 2, bufC + 16384);
      BAR();
      LGKM0();
      SB0();
      mfmaq<4, 0>(acc, afr, bfr);
      BAR();

      // ---- q3: zero reads; stage B(kt+2)h1 + A(kt+2)h0; counted vmcnt after MFMA
      if (kt < 14) {
        STAGE(Bbase, 1, kt + 2, bufC + 24576);
        STAGE(Abase, 0, kt + 2, bufC + 0);
      }
      SB0();
      mfmaq<4, 2>(acc, afr, bfr);
      SB0();
      if (kt < 14) {
        asm volatile("s_waitcnt vmcnt(6)" ::: "memory");  // retires A(kt+1)h1
      } else if (kt == 14) {
        asm volatile("s_waitcnt vmcnt(0)" ::: "memory");  // tail: A(15) must land
      }
      BAR();
    }

    // ---- epilogue: rule-weighted sigmoid -> LDS (bf16), 4-rule in-block reduce,
    // bf16 partial slice write (contention-free).
    __syncthreads();
    {
      unsigned short* yreg = sm + wn * 16384;  // [256][64], col-chunk ^= quad
#pragma unroll
      for (int mi = 0; mi < 8; ++mi) {
#pragma unroll
        for (int r = 0; r < 4; ++r) {
          int row = wm * 128 + mi * 16 + quad * 4 + r;
          float lamv = lamsh[row * 4 + wn];
#pragma unroll
          for (int ni = 0; ni < 4; ++ni) {
            float sg = 1.f / (1.f + __expf(-acc[mi][ni][r]));
            yreg[row * 64 + ((ni ^ quad) * 16) + l16] = f2bf(lamv * sg);
          }
        }
      }
    }
    __syncthreads();
    {
      unsigned short* pb = partial + (size_t)bx * SO + (size_t)gm0 * 64;
#pragma unroll
      for (int g = 0; g < 4; ++g) {
        int idx = g * 4096 + t * 8;  // lane-contiguous
        int row = idx >> 6;
        int c = idx & 63;
        int phys = row * 64 + ((((c >> 4) ^ ((row >> 2) & 3))) << 4) + (c & 15);
        float s[8];
#pragma unroll
        for (int jj = 0; jj < 8; ++jj) s[jj] = 0.f;
#pragma unroll
        for (int q = 0; q < 4; ++q) {
          ushx8 v = *(const ushx8*)(sm + q * 16384 + phys);
#pragma unroll
          for (int jj = 0; jj < 8; ++jj) s[jj] += bf2f(v[jj]);
        }
        ushx8 o;
#pragma unroll
        for (int jj = 0; jj < 8; ++jj) o[jj] = f2bf(s[jj]);
        *(ushx8*)(pb + idx) = o;
      }
    }

    // ---- last-arriver stripe reduce: 16th finisher of stripe 'by' sums the 16
    // bx-slices and writes Y rows gm0..gm0+255. rep0 reduces overlap rep1 compute.
    __threadfence();   // release our partial slice
    __syncthreads();
    if (t == 0) lastFlag = (atomicAdd(&ctr[1 + by], 1) == NSLICE - 1);
    __syncthreads();
    if (lastFlag) {
      __threadfence();  // acquire all 16 slices
      const unsigned short* pb0 = partial + (size_t)gm0 * 64;
      float* Yb = Y + (size_t)gm0 * 64;
#pragma unroll
      for (int g = 0; g < 4; ++g) {
        int idx = g * 4096 + t * 8;
        float s[8];
#pragma unroll
        for (int jj = 0; jj < 8; ++jj) s[jj] = 0.f;
#pragma unroll 4
        for (int sl = 0; sl < NSLICE; ++sl) {
          ushx8 v = *(const ushx8*)(pb0 + (size_t)sl * SO + idx);
#pragma unroll
          for (int jj = 0; jj < 8; ++jj) s[jj] += bf2f(v[jj]);
        }
        float4 lo = (float4){s[0], s[1], s[2], s[3]};
        float4 hi = (float4){s[4], s[5], s[6], s[7]};
        *(float4*)(Yb + idx) = lo;
        *(float4*)(Yb + idx + 4) = hi;
      }
    }
  }
}

extern "C" void kernel_launch(void* const* d_in, const int* in_sizes, int n_in,
                              void* d_out, int out_size, void* d_ws, size_t ws_size,
                              hipStream_t stream) {
  const float* X = (const float*)d_in[0];     // [8192,1024]
  const float* W = (const float*)d_in[1];     // [4096,1024]
  const float* b = (const float*)d_in[2];     // [4096]
  const float* lam = (const float*)d_in[3];   // [8192,64]
  float* Y = (float*)d_out;                   // [8192,64]

  unsigned short* Xb = (unsigned short*)d_ws;                 // 16 MB
  unsigned short* Wb = Xb + (size_t)S_DIM * K_DIM;            // 8 MB
  unsigned short* partial = Wb + (size_t)RO_DIM * K_DIM;      // 16 slices x 1 MB
  int* ctr = (int*)(partial + (size_t)NSLICE * SO);           // [33]: bar + done[32]

  hipMemsetAsync(ctr, 0, 33 * sizeof(int), stream);  // graph-capturable

  fused_kernel<<<dim3(256), dim3(512), 0, stream>>>(X, W, b, lam, Xb, Wb, partial, ctr, Y);
}

// Round 6
// 168.586 us; speedup vs baseline: 3.2249x; 3.2249x over previous
//
#include <hip/hip_runtime.h>

// Problem constants
#define S_DIM 8192
#define K_DIM 1024
#define RO_DIM 4096
#define O_DIM 64
#define SO (S_DIM * O_DIM)
#define NSLICE 16  // N/256 partial slices

typedef __attribute__((ext_vector_type(8))) __bf16 bf16x8;
typedef __attribute__((ext_vector_type(4))) float floatx4;
typedef __attribute__((ext_vector_type(4))) unsigned short ushx4;
typedef __attribute__((ext_vector_type(8))) unsigned short ushx8;

__device__ inline unsigned short f2bf(float f) {
  unsigned u = __builtin_bit_cast(unsigned, f);
  u += 0x7fff + ((u >> 16) & 1);  // round-to-nearest-even
  return (unsigned short)(u >> 16);
}
__device__ inline float bf2f(unsigned short h) {
  unsigned u = ((unsigned)h) << 16;
  return __builtin_bit_cast(float, u);
}

// ---------------------------------------------------------------- cast X,W -> bf16
__global__ __launch_bounds__(256) void cast_kernel(const float* __restrict__ X,
                                                   const float* __restrict__ W,
                                                   unsigned short* __restrict__ Xb,
                                                   unsigned short* __restrict__ Wb) {
  const int NX4 = (S_DIM * K_DIM) / 4;
#pragma unroll
  for (int i = 0; i < 4; ++i) {
    int g = blockIdx.x * 1024 + i * 256 + threadIdx.x;
    float4 v;
    unsigned short* dst;
    if (g < NX4) {
      v = ((const float4*)X)[g];
      dst = Xb + (size_t)g * 4;
    } else {
      int j = g - NX4;
      v = ((const float4*)W)[j];
      dst = Wb + (size_t)j * 4;
    }
    ushx4 o;
    o.x = f2bf(v.x); o.y = f2bf(v.y); o.z = f2bf(v.z); o.w = f2bf(v.w);
    *(ushx4*)dst = o;
  }
}

// ---------------------------------------------------------------- 256x256 8-phase GEMM
// R6 vs R3 (R4/R5 fusion reverted — both fusion mechanisms lost 250+us to
// fence/L2-flush pathology; 3-kernel structure is the proven base):
// (1) REMOVED the per-phase lgkmcnt(0)+sched_barrier(0) pin. ds_reads here are
//     compiler-visible loads, so hipcc emits fine-grained lgkmcnt(4/3/1/0)
//     before each consuming MFMA (m97) — MFMAs start when their first operands
//     land instead of after all 12 reads drain, and the scheduler may overlap
//     residual LDS latency with the cluster (m141: pinning cost 874->510 TF).
//     WAR safety without the pin: each phase's MFMAs consume ALL its reads, so
//     lgkm has drained before a wave passes the phase-closing barrier; slots
//     are only overwritten by stages issued after that barrier.
// (2) MFMA cluster reordered k-outermost: consecutive MFMAs now hit different
//     accumulators (8 apart before same-acc reuse) — no in-order stall on the
//     ~20cy MFMA latency between the k0/k1 pair of the same acc.
// Everything else identical to R3: quadrant phases q0..q3 (q3 = zero-read),
// stages q0->A(kt+1)h1, q2->B(kt+2)h0, q3->B(kt+2)h1+A(kt+2)h0, vmcnt(6)
// after q3's MFMA (in-order retirement proof in R3), XOR k-chunk swizzle,
// XCD remap (XCD x owns bx in {2x,2x+1}; B 1MB/XCD L2-resident).

template <int MB, int NB>
__device__ __forceinline__ void mfmaq(floatx4 (&acc)[8][4], const bf16x8 (&afr)[4][2],
                                      const bf16x8 (&bfr)[4][2]) {
  __builtin_amdgcn_s_setprio(1);
#pragma unroll
  for (int ks = 0; ks < 2; ++ks)
#pragma unroll
    for (int m = 0; m < 4; ++m)
#pragma unroll
      for (int n = 0; n < 2; ++n)
        acc[MB + m][NB + n] = __builtin_amdgcn_mfma_f32_16x16x32_bf16(
            afr[m][ks], bfr[NB + n][ks], acc[MB + m][NB + n], 0, 0, 0);
  __builtin_amdgcn_s_setprio(0);
}

#define BAR() __builtin_amdgcn_s_barrier()

__global__ __launch_bounds__(512, 2) void gemm_kernel(const unsigned short* __restrict__ Xb,
                                                      const unsigned short* __restrict__ Wb,
                                                      const float* __restrict__ bias,
                                                      const float* __restrict__ lam,
                                                      unsigned short* __restrict__ partial) {
  __shared__ __align__(16) unsigned char smem[135168];  // 128KB buffers + 4KB lamsh
  unsigned short* sm = (unsigned short*)smem;
  float* lamsh = (float*)(smem + 131072);  // [256][4]

  const int t = threadIdx.x;
  const int lane = t & 63;
  const int w = t >> 6;
  const int wm = w >> 2;   // M half: rows wm*128..+127
  const int wn = w & 3;    // N quarter = rule index within block
  const int quad = lane >> 4;
  const int l16 = lane & 15;

  // XCD-locality remap: hw XCD = id%8. XCD x gets bx in {2x,2x+1}; pair sharing
  // an A panel (j even/odd) is 8 dispatch-ids apart -> co-resident on XCD x.
  int id = blockIdx.y * 16 + blockIdx.x;
  int x = id & 7;
  int j = id >> 3;               // 0..63
  const int bx = 2 * x + (j & 1);
  const int by = j >> 1;         // 0..31
  const int gm0 = by * 256;
  const int gn0 = bx * 256;

  // staging per-thread constants (gcc = chunk ^ (row&7) is thread-invariant)
  const int rowt = t >> 3;                       // 0..63
  const int gcc = (t & 7) ^ (rowt & 7);
  const size_t goff = (size_t)rowt * K_DIM + (size_t)gcc * 8;
  const unsigned short* Abase = Xb + (size_t)gm0 * K_DIM;
  const unsigned short* Bbase = Wb + (size_t)gn0 * K_DIM;

  auto STAGE = [&](const unsigned short* gbase, int half, int ktile, int slotOff) {
#pragma unroll
    for (int jj = 0; jj < 2; ++jj) {
      const unsigned short* src =
          gbase + (size_t)(half * 128 + jj * 64) * K_DIM + ktile * 64 + goff;
      __builtin_amdgcn_global_load_lds(
          (const __attribute__((address_space(1))) void*)src,
          (__attribute__((address_space(3))) void*)(sm + slotOff + jj * 4096 + t * 8),
          16, 0, 0);
    }
  };

  // prologue: tile0 full (buf0), tile1 B halves + A h0 (buf1): 14 loads.
  STAGE(Abase, 0, 0, 0);
  STAGE(Abase, 1, 0, 8192);
  STAGE(Bbase, 0, 0, 16384);
  STAGE(Bbase, 1, 0, 24576);
  STAGE(Bbase, 0, 1, 32768 + 16384);
  STAGE(Bbase, 1, 1, 32768 + 24576);
  STAGE(Abase, 0, 1, 32768 + 0);

  {
    int i = t;
    lamsh[i] = lam[(size_t)(gm0 + (i >> 2)) * 64 + bx * 4 + (i & 3)];
    i = t + 512;
    lamsh[i] = lam[(size_t)(gm0 + (i >> 2)) * 64 + bx * 4 + (i & 3)];
  }
  // retire tile0's 8 loads (+B1h0); leaves <=6: B1h1, A1h0, lam
  asm volatile("s_waitcnt vmcnt(6)" ::: "memory");
  BAR();

  // acc init = bias (exact fold); bias loads sit in the vmcnt window as OLDER
  // ops than all loop stages -> every later counted wait only tightens.
  floatx4 acc[8][4];
#pragma unroll
  for (int ni = 0; ni < 4; ++ni) {
    float bv = bias[gn0 + wn * 64 + ni * 16 + l16];
#pragma unroll
    for (int mi = 0; mi < 8; ++mi) acc[mi][ni] = (floatx4){bv, bv, bv, bv};
  }

  const int cA0 = ((quad) ^ (l16 & 7)) * 8;        // k-chunk ks=0, swizzled
  const int cA1 = ((4 + quad) ^ (l16 & 7)) * 8;    // k-chunk ks=1, swizzled

  for (int kt = 0; kt < 16; ++kt) {
    const int b = kt & 1;
    const unsigned short* As = sm + b * 32768 + wm * 8192 + l16 * 64;
    const unsigned short* Bs = sm + b * 32768 + 16384 + wn * 4096 + l16 * 64;
    const int bufN = (b ^ 1) * 32768;  // tile kt+1's buffer
    const int bufC = b * 32768;        // tile kt+2's buffer (== current)

    bf16x8 afr[4][2], bfr[4][2];

    // ---- q0: read A mi0-3 + B ni0-1; stage A(kt+1) h1
#pragma unroll
    for (int m = 0; m < 4; ++m) {
      afr[m][0] = *(const bf16x8*)(As + m * 1024 + cA0);
      afr[m][1] = *(const bf16x8*)(As + m * 1024 + cA1);
    }
#pragma unroll
    for (int n = 0; n < 2; ++n) {
      bfr[n][0] = *(const bf16x8*)(Bs + n * 1024 + cA0);
      bfr[n][1] = *(const bf16x8*)(Bs + n * 1024 + cA1);
    }
    if (kt < 15) STAGE(Abase, 1, kt + 1, bufN + 8192);
    BAR();
    mfmaq<0, 0>(acc, afr, bfr);
    BAR();

    // ---- q1: read B ni2-3 (B halves still being read -> no B stage here)
#pragma unroll
    for (int n = 2; n < 4; ++n) {
      bfr[n][0] = *(const bf16x8*)(Bs + n * 1024 + cA0);
      bfr[n][1] = *(const bf16x8*)(Bs + n * 1024 + cA1);
    }
    BAR();
    mfmaq<0, 2>(acc, afr, bfr);
    BAR();

    // ---- q2: read A mi4-7; stage B(kt+2) h0 (B slots free after q1)
#pragma unroll
    for (int m = 0; m < 4; ++m) {
      afr[m][0] = *(const bf16x8*)(As + (4 + m) * 1024 + cA0);
      afr[m][1] = *(const bf16x8*)(As + (4 + m) * 1024 + cA1);
    }
    if (kt < 14) STAGE(Bbase, 0, kt + 2, bufC + 16384);
    BAR();
    mfmaq<4, 0>(acc, afr, bfr);
    BAR();

    // ---- q3: zero reads; stage B(kt+2) h1 + A(kt+2) h0 (A slots free after q2);
    // pure-MFMA phase hosts the counted wait AFTER the cluster.
    if (kt < 14) {
      STAGE(Bbase, 1, kt + 2, bufC + 24576);
      STAGE(Abase, 0, kt + 2, bufC + 0);
    }
    mfmaq<4, 2>(acc, afr, bfr);
    if (kt < 14) {
      asm volatile("s_waitcnt vmcnt(6)" ::: "memory");  // retires A(kt+1)h1
    } else if (kt == 14) {
      asm volatile("s_waitcnt vmcnt(0)" ::: "memory");  // tail: A(15) must land
    }
    BAR();
  }

  // ---- epilogue: rule-weighted sigmoid -> LDS (bf16), 4-rule in-block reduce,
  // bf16 partial slice write (contention-free; reduce kernel finishes).
  __syncthreads();
  {
    unsigned short* yreg = sm + wn * 16384;  // [256][64], col-chunk ^= quad (banks)
#pragma unroll
    for (int mi = 0; mi < 8; ++mi) {
#pragma unroll
      for (int r = 0; r < 4; ++r) {
        int row = wm * 128 + mi * 16 + quad * 4 + r;
        float lamv = lamsh[row * 4 + wn];
#pragma unroll
        for (int ni = 0; ni < 4; ++ni) {
          float sg = 1.f / (1.f + __expf(-acc[mi][ni][r]));
          yreg[row * 64 + ((ni ^ quad) * 16) + l16] = f2bf(lamv * sg);
        }
      }
    }
  }
  __syncthreads();
  {
    unsigned short* pb = partial + (size_t)bx * SO + (size_t)gm0 * 64;
#pragma unroll
    for (int g = 0; g < 4; ++g) {
      int idx = g * 4096 + t * 8;  // lane-contiguous
      int row = idx >> 6;
      int c = idx & 63;
      int phys = row * 64 + ((((c >> 4) ^ ((row >> 2) & 3))) << 4) + (c & 15);
      float s[8];
#pragma unroll
      for (int jj = 0; jj < 8; ++jj) s[jj] = 0.f;
#pragma unroll
      for (int q = 0; q < 4; ++q) {
        ushx8 v = *(const ushx8*)(sm + q * 16384 + phys);
#pragma unroll
        for (int jj = 0; jj < 8; ++jj) s[jj] += bf2f(v[jj]);
      }
      ushx8 o;
#pragma unroll
      for (int jj = 0; jj < 8; ++jj) o[jj] = f2bf(s[jj]);
      *(ushx8*)(pb + idx) = o;
    }
  }
}

// ---------------------------------------------------------------- final reduce over 16 N-tiles
__global__ __launch_bounds__(256) void reduce_kernel(const unsigned short* __restrict__ partial,
                                                     float* __restrict__ Y) {
  int i4 = blockIdx.x * 256 + threadIdx.x;
  float s0 = 0.f, s1 = 0.f, s2 = 0.f, s3 = 0.f;
#pragma unroll
  for (int c = 0; c < NSLICE; ++c) {
    ushx4 v = ((const ushx4*)(partial + (size_t)c * SO))[i4];
    s0 += bf2f(v.x); s1 += bf2f(v.y); s2 += bf2f(v.z); s3 += bf2f(v.w);
  }
  ((float4*)Y)[i4] = (float4){s0, s1, s2, s3};
}

extern "C" void kernel_launch(void* const* d_in, const int* in_sizes, int n_in,
                              void* d_out, int out_size, void* d_ws, size_t ws_size,
                              hipStream_t stream) {
  const float* X = (const float*)d_in[0];     // [8192,1024]
  const float* W = (const float*)d_in[1];     // [4096,1024]
  const float* b = (const float*)d_in[2];     // [4096]
  const float* lam = (const float*)d_in[3];   // [8192,64]
  float* Y = (float*)d_out;                   // [8192,64]

  unsigned short* Xb = (unsigned short*)d_ws;                 // 16 MB
  unsigned short* Wb = Xb + (size_t)S_DIM * K_DIM;            // 8 MB
  unsigned short* partial = Wb + (size_t)RO_DIM * K_DIM;      // 16 slices x 1 MB

  int nCast = ((S_DIM + RO_DIM) * K_DIM / 4) / 1024;  // 3072 blocks
  cast_kernel<<<nCast, 256, 0, stream>>>(X, W, Xb, Wb);

  dim3 g(RO_DIM / 256, S_DIM / 256);  // (16, 32) = 512 blocks, 512 threads
  gemm_kernel<<<g, 512, 0, stream>>>(Xb, Wb, b, lam, partial);

  reduce_kernel<<<SO / 1024, 256, 0, stream>>>(partial, Y);
}

// Round 7
// 166.299 us; speedup vs baseline: 3.2693x; 1.0138x over previous
//
#include <hip/hip_runtime.h>

// Problem constants
#define S_DIM 8192
#define K_DIM 1024
#define RO_DIM 4096
#define O_DIM 64
#define SO (S_DIM * O_DIM)
#define NSLICE 16  // N/256 partial slices

typedef __attribute__((ext_vector_type(8))) __bf16 bf16x8;
typedef __attribute__((ext_vector_type(4))) float floatx4;
typedef __attribute__((ext_vector_type(4))) unsigned short ushx4;
typedef __attribute__((ext_vector_type(8))) unsigned short ushx8;

__device__ inline unsigned short f2bf(float f) {
  unsigned u = __builtin_bit_cast(unsigned, f);
  u += 0x7fff + ((u >> 16) & 1);  // round-to-nearest-even
  return (unsigned short)(u >> 16);
}
__device__ inline float bf2f(unsigned short h) {
  unsigned u = ((unsigned)h) << 16;
  return __builtin_bit_cast(float, u);
}

// ---------------------------------------------------------------- cast X,W -> bf16
__global__ __launch_bounds__(256) void cast_kernel(const float* __restrict__ X,
                                                   const float* __restrict__ W,
                                                   unsigned short* __restrict__ Xb,
                                                   unsigned short* __restrict__ Wb) {
  const int NX4 = (S_DIM * K_DIM) / 4;
#pragma unroll
  for (int i = 0; i < 4; ++i) {
    int g = blockIdx.x * 1024 + i * 256 + threadIdx.x;
    float4 v;
    unsigned short* dst;
    if (g < NX4) {
      v = ((const float4*)X)[g];
      dst = Xb + (size_t)g * 4;
    } else {
      int j = g - NX4;
      v = ((const float4*)W)[j];
      dst = Wb + (size_t)j * 4;
    }
    ushx4 o;
    o.x = f2bf(v.x); o.y = f2bf(v.y); o.z = f2bf(v.z); o.w = f2bf(v.w);
    *(ushx4*)dst = o;
  }
}

// ---------------------------------------------------------------- 256x256 GEMM, reg-dbuf fragments
// R7 vs R6: fragment-register double-buffering. Cycle accounting showed the two
// big pipes are LDS-read (~2300 cyc/CU/k-tile: 192x ds_read_b128) and MFMA
// (~2480 cyc) but measured 5800 -> serialized, because each phase's MFMA
// consumed reads issued in the SAME phase (lgkm wait on the critical path,
// barrier convoy). Now each phase issues the NEXT phase's reads, so MFMA(q)
// runs on regs loaded at q-1 while reads(q+1) drain underneath:
//   q0-body: read bf23(4)            | stage A(kt+1)h1 | MFMA q0 (af0,bf01)
//   q1-body: read af1(8)             | stage B(kt+2)h0 | MFMA q1 (af0,bf23)
//   q2-body: (no reads)              | stage B(kt+2)h1 | MFMA q2 (af1,bf01)
//   q3-body: stage A(kt+2)h0; vmcnt(6); read next af0+bf01(12) | MFMA q3 (af1,bf23)
// vmcnt(6) proof unchanged (R3): at q3 the 8 outstanding are the 4 stages of
// this tile + A(kt+1)h1; vmcnt(6) retires exactly A(kt+1)h1 -> ALL of tile
// kt+1 landed -> next-tile prefetch reads (issued after the vmcnt asm, which
// blocks code motion) are safe. WAR per-region: every stage that overwrites a
// prefetched region issues >=2 barriers after the read's consuming MFMA.
// Tail: kt=14 -> vmcnt(0) before tile-15 prefetch; kt=15 stages/prefetches none.
// Regs: 24 live frags (af0,af1,bf01,bf23 = 96 VGPR) + acc 128 -> ~190, fits
// 2 waves/SIMD. Kept from R6: k-outermost MFMA order, setprio, XOR k-chunk
// swizzle, XCD remap (XCD x owns bx in {2x,2x+1}), epilogue, 3-kernel split.

template <int MB, int NB>
__device__ __forceinline__ void mfmaq(floatx4 (&acc)[8][4], const bf16x8 (&af)[4][2],
                                      const bf16x8 (&bf)[2][2]) {
  __builtin_amdgcn_s_setprio(1);
#pragma unroll
  for (int ks = 0; ks < 2; ++ks)
#pragma unroll
    for (int m = 0; m < 4; ++m)
#pragma unroll
      for (int n = 0; n < 2; ++n)
        acc[MB + m][NB + n] = __builtin_amdgcn_mfma_f32_16x16x32_bf16(
            af[m][ks], bf[n][ks], acc[MB + m][NB + n], 0, 0, 0);
  __builtin_amdgcn_s_setprio(0);
}

__device__ __forceinline__ void rdA(bf16x8 (&af)[4][2], const unsigned short* As,
                                    int mbase, int cA0, int cA1) {
#pragma unroll
  for (int m = 0; m < 4; ++m) {
    af[m][0] = *(const bf16x8*)(As + (mbase + m) * 1024 + cA0);
    af[m][1] = *(const bf16x8*)(As + (mbase + m) * 1024 + cA1);
  }
}
__device__ __forceinline__ void rdB(bf16x8 (&bf)[2][2], const unsigned short* Bs,
                                    int nbase, int cA0, int cA1) {
#pragma unroll
  for (int n = 0; n < 2; ++n) {
    bf[n][0] = *(const bf16x8*)(Bs + (nbase + n) * 1024 + cA0);
    bf[n][1] = *(const bf16x8*)(Bs + (nbase + n) * 1024 + cA1);
  }
}

#define BAR() __builtin_amdgcn_s_barrier()

__global__ __launch_bounds__(512, 2) void gemm_kernel(const unsigned short* __restrict__ Xb,
                                                      const unsigned short* __restrict__ Wb,
                                                      const float* __restrict__ bias,
                                                      const float* __restrict__ lam,
                                                      unsigned short* __restrict__ partial) {
  __shared__ __align__(16) unsigned char smem[135168];  // 128KB buffers + 4KB lamsh
  unsigned short* sm = (unsigned short*)smem;
  float* lamsh = (float*)(smem + 131072);  // [256][4]

  const int t = threadIdx.x;
  const int lane = t & 63;
  const int w = t >> 6;
  const int wm = w >> 2;   // M half: rows wm*128..+127
  const int wn = w & 3;    // N quarter = rule index within block
  const int quad = lane >> 4;
  const int l16 = lane & 15;

  // XCD-locality remap: hw XCD = id%8. XCD x gets bx in {2x,2x+1}.
  int id = blockIdx.y * 16 + blockIdx.x;
  int x = id & 7;
  int j = id >> 3;               // 0..63
  const int bx = 2 * x + (j & 1);
  const int by = j >> 1;         // 0..31
  const int gm0 = by * 256;
  const int gn0 = bx * 256;

  // staging per-thread constants (gcc = chunk ^ (row&7) is thread-invariant)
  const int rowt = t >> 3;                       // 0..63
  const int gcc = (t & 7) ^ (rowt & 7);
  const size_t goff = (size_t)rowt * K_DIM + (size_t)gcc * 8;
  const unsigned short* Abase = Xb + (size_t)gm0 * K_DIM;
  const unsigned short* Bbase = Wb + (size_t)gn0 * K_DIM;

  auto STAGE = [&](const unsigned short* gbase, int half, int ktile, int slotOff) {
#pragma unroll
    for (int jj = 0; jj < 2; ++jj) {
      const unsigned short* src =
          gbase + (size_t)(half * 128 + jj * 64) * K_DIM + ktile * 64 + goff;
      __builtin_amdgcn_global_load_lds(
          (const __attribute__((address_space(1))) void*)src,
          (__attribute__((address_space(3))) void*)(sm + slotOff + jj * 4096 + t * 8),
          16, 0, 0);
    }
  };

  // prologue: tile0 full (buf0), tile1 B halves + A h0 (buf1): 14 loads.
  STAGE(Abase, 0, 0, 0);
  STAGE(Abase, 1, 0, 8192);
  STAGE(Bbase, 0, 0, 16384);
  STAGE(Bbase, 1, 0, 24576);
  STAGE(Bbase, 0, 1, 32768 + 16384);
  STAGE(Bbase, 1, 1, 32768 + 24576);
  STAGE(Abase, 0, 1, 32768 + 0);

  {
    int i = t;
    lamsh[i] = lam[(size_t)(gm0 + (i >> 2)) * 64 + bx * 4 + (i & 3)];
    i = t + 512;
    lamsh[i] = lam[(size_t)(gm0 + (i >> 2)) * 64 + bx * 4 + (i & 3)];
  }
  // retire tile0's 8 loads; leaves 6: B1h0, B1h1, A1h0 (+lam scalar-domain)
  asm volatile("s_waitcnt vmcnt(6)" ::: "memory");
  BAR();

  // acc init = bias (exact fold); bias loads are older than all loop stages.
  floatx4 acc[8][4];
#pragma unroll
  for (int ni = 0; ni < 4; ++ni) {
    float bv = bias[gn0 + wn * 64 + ni * 16 + l16];
#pragma unroll
    for (int mi = 0; mi < 8; ++mi) acc[mi][ni] = (floatx4){bv, bv, bv, bv};
  }

  const int cA0 = ((quad) ^ (l16 & 7)) * 8;        // k-chunk ks=0, swizzled
  const int cA1 = ((4 + quad) ^ (l16 & 7)) * 8;    // k-chunk ks=1, swizzled

  const int Aoff = wm * 8192 + l16 * 64;
  const int Boff = 16384 + wn * 4096 + l16 * 64;

  bf16x8 af0[4][2], af1[4][2], bf01[2][2], bf23[2][2];

  // prologue prefetch: tile0 q0 operands (af0 = A mi0-3, bf01 = B ni0-1)
  rdA(af0, sm + Aoff, 0, cA0, cA1);
  rdB(bf01, sm + Boff, 0, cA0, cA1);

  for (int kt = 0; kt < 16; ++kt) {
    const int b = kt & 1;
    const unsigned short* As = sm + b * 32768 + Aoff;
    const unsigned short* Bs = sm + b * 32768 + Boff;
    const unsigned short* AsN = sm + (b ^ 1) * 32768 + Aoff;  // next tile
    const unsigned short* BsN = sm + (b ^ 1) * 32768 + Boff;
    const int bufN = (b ^ 1) * 32768;  // tile kt+1's buffer
    const int bufC = b * 32768;        // tile kt+2's buffer (== current)

    // ---- q0-body: prefetch q1 operands (bf23); stage A(kt+1)h1; MFMA q0
    rdB(bf23, Bs, 2, cA0, cA1);
    if (kt < 15) STAGE(Abase, 1, kt + 1, bufN + 8192);
    BAR();
    mfmaq<0, 0>(acc, af0, bf01);
    BAR();

    // ---- q1-body: prefetch q2 operands (af1); stage B(kt+2)h0; MFMA q1
    rdA(af1, As, 4, cA0, cA1);
    if (kt < 14) STAGE(Bbase, 0, kt + 2, bufC + 16384);
    BAR();
    mfmaq<0, 2>(acc, af0, bf23);
    BAR();

    // ---- q2-body: no reads; stage B(kt+2)h1; MFMA q2
    if (kt < 14) STAGE(Bbase, 1, kt + 2, bufC + 24576);
    BAR();
    mfmaq<4, 0>(acc, af1, bf01);
    BAR();

    // ---- q3-body: stage A(kt+2)h0; counted vmcnt; prefetch NEXT tile q0
    // operands (af0, bf01 from buffer b^1 — proven landed by the vmcnt); MFMA q3
    if (kt < 14) {
      STAGE(Abase, 0, kt + 2, bufC + 0);
      asm volatile("s_waitcnt vmcnt(6)" ::: "memory");  // retires A(kt+1)h1
    } else if (kt == 14) {
      asm volatile("s_waitcnt vmcnt(0)" ::: "memory");  // tail: tile 15 all landed
    }
    if (kt < 15) {
      rdA(af0, AsN, 0, cA0, cA1);
      rdB(bf01, BsN, 0, cA0, cA1);
    }
    BAR();
    mfmaq<4, 2>(acc, af1, bf23);
    BAR();
  }

  // ---- epilogue: rule-weighted sigmoid -> LDS (bf16), 4-rule in-block reduce,
  // bf16 partial slice write (contention-free; reduce kernel finishes).
  __syncthreads();
  {
    unsigned short* yreg = sm + wn * 16384;  // [256][64], col-chunk ^= quad (banks)
#pragma unroll
    for (int mi = 0; mi < 8; ++mi) {
#pragma unroll
      for (int r = 0; r < 4; ++r) {
        int row = wm * 128 + mi * 16 + quad * 4 + r;
        float lamv = lamsh[row * 4 + wn];
#pragma unroll
        for (int ni = 0; ni < 4; ++ni) {
          float sg = 1.f / (1.f + __expf(-acc[mi][ni][r]));
          yreg[row * 64 + ((ni ^ quad) * 16) + l16] = f2bf(lamv * sg);
        }
      }
    }
  }
  __syncthreads();
  {
    unsigned short* pb = partial + (size_t)bx * SO + (size_t)gm0 * 64;
#pragma unroll
    for (int g = 0; g < 4; ++g) {
      int idx = g * 4096 + t * 8;  // lane-contiguous
      int row = idx >> 6;
      int c = idx & 63;
      int phys = row * 64 + ((((c >> 4) ^ ((row >> 2) & 3))) << 4) + (c & 15);
      float s[8];
#pragma unroll
      for (int jj = 0; jj < 8; ++jj) s[jj] = 0.f;
#pragma unroll
      for (int q = 0; q < 4; ++q) {
        ushx8 v = *(const ushx8*)(sm + q * 16384 + phys);
#pragma unroll
        for (int jj = 0; jj < 8; ++jj) s[jj] += bf2f(v[jj]);
      }
      ushx8 o;
#pragma unroll
      for (int jj = 0; jj < 8; ++jj) o[jj] = f2bf(s[jj]);
      *(ushx8*)(pb + idx) = o;
    }
  }
}

// ---------------------------------------------------------------- final reduce over 16 N-tiles
__global__ __launch_bounds__(256) void reduce_kernel(const unsigned short* __restrict__ partial,
                                                     float* __restrict__ Y) {
  int i4 = blockIdx.x * 256 + threadIdx.x;
  float s0 = 0.f, s1 = 0.f, s2 = 0.f, s3 = 0.f;
#pragma unroll
  for (int c = 0; c < NSLICE; ++c) {
    ushx4 v = ((const ushx4*)(partial + (size_t)c * SO))[i4];
    s0 += bf2f(v.x); s1 += bf2f(v.y); s2 += bf2f(v.z); s3 += bf2f(v.w);
  }
  ((float4*)Y)[i4] = (float4){s0, s1, s2, s3};
}

extern "C" void kernel_launch(void* const* d_in, const int* in_sizes, int n_in,
                              void* d_out, int out_size, void* d_ws, size_t ws_size,
                              hipStream_t stream) {
  const float* X = (const float*)d_in[0];     // [8192,1024]
  const float* W = (const float*)d_in[1];     // [4096,1024]
  const float* b = (const float*)d_in[2];     // [4096]
  const float* lam = (const float*)d_in[3];   // [8192,64]
  float* Y = (float*)d_out;                   // [8192,64]

  unsigned short* Xb = (unsigned short*)d_ws;                 // 16 MB
  unsigned short* Wb = Xb + (size_t)S_DIM * K_DIM;            // 8 MB
  unsigned short* partial = Wb + (size_t)RO_DIM * K_DIM;      // 16 slices x 1 MB

  int nCast = ((S_DIM + RO_DIM) * K_DIM / 4) / 1024;  // 3072 blocks
  cast_kernel<<<nCast, 256, 0, stream>>>(X, W, Xb, Wb);

  dim3 g(RO_DIM / 256, S_DIM / 256);  // (16, 32) = 512 blocks, 512 threads
  gemm_kernel<<<g, 512, 0, stream>>>(Xb, Wb, b, lam, partial);

  reduce_kernel<<<SO / 1024, 256, 0, stream>>>(partial, Y);
}